// Round 3
// baseline (309.563 us; speedup 1.0000x reference)
//
#include <hip/hip_runtime.h>
#include <math.h>

#define DIM 96
#define NE 6
#define NB 8
#define H 192
#define W 192
#define HW (H * W)
#define NQ 4            // pool partial quarters
#define QF4 (HW / 4 / NQ)  // 2304 float4 per quarter

// ---------------- Kernel A: partial max+sum per (b,c,quarter) ----------------
__global__ __launch_bounds__(256) void pool_partial(const float* __restrict__ x,
                                                    float* __restrict__ pmax,
                                                    float* __restrict__ psum) {
    int bc = blockIdx.x;       // 0..767
    int q = blockIdx.y;        // 0..3
    const float4* xp = (const float4*)(x + (size_t)bc * HW) + q * QF4;
    int tid = threadIdx.x;
    float vmax = -INFINITY, vsum = 0.f;
    for (int i = tid; i < QF4; i += 256) {
        float4 v = xp[i];
        vmax = fmaxf(vmax, fmaxf(fmaxf(v.x, v.y), fmaxf(v.z, v.w)));
        vsum += v.x + v.y + v.z + v.w;
    }
    for (int off = 32; off; off >>= 1) {
        vmax = fmaxf(vmax, __shfl_down(vmax, off, 64));
        vsum += __shfl_down(vsum, off, 64);
    }
    __shared__ float smax[4], ssum[4];
    if ((tid & 63) == 0) { smax[tid >> 6] = vmax; ssum[tid >> 6] = vsum; }
    __syncthreads();
    if (tid == 0) {
        float m = smax[0], s = ssum[0];
        for (int w = 1; w < 4; ++w) { m = fmaxf(m, smax[w]); s += ssum[w]; }
        pmax[q * (NB * DIM) + bc] = m;
        psum[q * (NB * DIM) + bc] = s;
    }
}

// ---------------- Kernel B: gate (parallel dots from LDS) ----------------
__global__ __launch_bounds__(128) void gate_kernel(const float* __restrict__ pmax,
                                                   const float* __restrict__ psum,
                                                   const float* __restrict__ w_fc0,
                                                   const float* __restrict__ b_fc0,
                                                   const float* __restrict__ w_fc1,
                                                   const float* __restrict__ b_fc1,
                                                   float* __restrict__ cof) {
    __shared__ float sp[NB * DIM];       // pooled
    __shared__ float sw1[NE * DIM], sw0[NE * DIM];
    __shared__ float z1s[NB * NE], z0s[NB * NE];
    int tid = threadIdx.x;
    for (int i = tid; i < NB * DIM; i += 128) {
        float m = pmax[i], s = psum[i];
        for (int q = 1; q < NQ; ++q) {
            m = fmaxf(m, pmax[q * (NB * DIM) + i]);
            s += psum[q * (NB * DIM) + i];
        }
        sp[i] = m + s * (1.0f / (float)HW);
    }
    for (int i = tid; i < NE * DIM; i += 128) {
        sw1[i] = w_fc1[i];
        sw0[i] = w_fc0[i];
    }
    __syncthreads();
    if (tid < 2 * NB * NE) {             // 96 threads: one dot each
        int pair = (tid < NB * NE) ? tid : tid - NB * NE;
        int b = pair / NE, e = pair - b * NE;
        const float* wp = ((tid < NB * NE) ? sw1 : sw0) + e * DIM;
        float z = (tid < NB * NE) ? b_fc1[e] : b_fc0[e];
        const float* pp = sp + b * DIM;
        for (int i = 0; i < DIM; ++i) z = fmaf(pp[i], wp[i], z);
        if (tid < NB * NE) z1s[pair] = z; else z0s[pair] = z;
    }
    __syncthreads();
    if (tid < NB) {
        int b = tid;
        float g[NE], noise[NE];
        for (int e = 0; e < NE; ++e) {
            float z1 = z1s[b * NE + e], z0 = z0s[b * NE + e];
            g[e] = (z1 > 0.f) ? z1 : 0.2f * z1;                 // leaky_relu 0.2
            noise[e] = (z0 > 20.f) ? z0 : log1pf(expf(z0));     // softplus
        }
        float mu = 0.f;
        for (int e = 0; e < NE; ++e) mu += noise[e];
        mu *= (1.0f / NE);
        float var = 0.f;
        for (int e = 0; e < NE; ++e) { float d = noise[e] - mu; var += d * d; }
        var *= (1.0f / (NE - 1));                               // ddof=1
        float sd = sqrtf(var);
        float scores[NE];
        for (int e = 0; e < NE; ++e) scores[e] = g[e] + (noise[e] - mu) / sd;
        bool chosen[NE] = {false, false, false, false, false, false};
        for (int k = 0; k < 3; ++k) {                           // top-3, ties -> lowest idx
            float best = -INFINITY; int bi = 0;
            for (int e = 0; e < NE; ++e)
                if (!chosen[e] && scores[e] > best) { best = scores[e]; bi = e; }
            chosen[bi] = true;
        }
        float m = -INFINITY;
        for (int e = 0; e < NE; ++e) if (chosen[e]) m = fmaxf(m, g[e]);
        float s = 0.f;
        for (int e = 0; e < NE; ++e) if (chosen[e]) s += expf(g[e] - m);
        float inv = 1.0f / s;
        for (int e = 0; e < NE; ++e)
            cof[b * NE + e] = chosen[e] ? expf(g[e] - m) * inv : 0.f;
    }
}

// ---------------- Kernel C: fused top-k expert dwconv-relu-dwconv ----------------
// Tile 64x32. xs: input + 2-halo (36x68). ys: conv1 out + 1-halo (34x68, cols 0..65 valid).
// Threads: 16 row-pairs (g) x 16 quad-cols (q). Each thread: 4 cols x 2 rows per conv.
// Windows [4q .. 4q+5] are b128+b64 aligned because halo offsets are 2 (xs) / 1 (ys).
#define TX 64
#define TY 32
#define IX 68
#define IY 36
#define YSX 68   // padded leading dim (valid cols 0..65)
#define YSY 34

__global__ __launch_bounds__(256) void moe_kernel(const float* __restrict__ x,
                                                  const float* __restrict__ ew1,
                                                  const float* __restrict__ eb1,
                                                  const float* __restrict__ ew2,
                                                  const float* __restrict__ eb2,
                                                  const float* __restrict__ cof,
                                                  float* __restrict__ out) {
    __shared__ float xs[IY][IX];
    __shared__ float ys[YSY][YSX];
    const int tile = blockIdx.x;                 // 0..17
    const int c = blockIdx.y;
    const int b = blockIdx.z;
    const int tx0 = (tile % (W / TX)) * TX;
    const int ty0 = (tile / (W / TX)) * TY;
    const int tid = threadIdx.x;
    const int tx = tid & 63;
    const int wv = tid >> 6;
    const int q = tid & 15;                      // quad col: cols 4q..4q+3
    const int g = tid >> 4;                      // row pair: rows 2g, 2g+1

    const float* xp = x + ((size_t)(b * DIM + c)) * HW;

    // ---- stage x tile + 2-halo ----
    #pragma unroll
    for (int rr = 0; rr < 9; ++rr) {
        int r = wv + rr * 4;                     // 0..35
        int gh = ty0 + r - 2;
        int gw = tx0 + tx - 2;
        float v = 0.f, v2 = 0.f;
        if (gh >= 0 && gh < H) {
            if (gw >= 0 && gw < W) v = xp[gh * W + gw];
            int gw2 = gw + 64;
            if (tx < 4 && gw2 < W) v2 = xp[gh * W + gw2];
        }
        xs[r][tx] = v;
        if (tx < 4) xs[r][tx + 64] = v2;
    }

    const bool topB = (ty0 == 0), botB = (ty0 == H - TY);
    const bool leftB = (tx0 == 0), rightB = (tx0 == W - TX);

    float acc0[4] = {0.f, 0.f, 0.f, 0.f};
    float acc1[4] = {0.f, 0.f, 0.f, 0.f};

    for (int e = 0; e < NE; ++e) {
        float ce = cof[b * NE + e];              // block-uniform -> uniform branch
        if (ce == 0.f) continue;
        const float* w1p = ew1 + (size_t)(e * DIM + c) * 9;
        const float* w2p = ew2 + (size_t)(e * DIM + c) * 9;
        float w1r[9], w2r[9];
        #pragma unroll
        for (int k = 0; k < 9; ++k) { w1r[k] = w1p[k]; w2r[k] = w2p[k]; }
        const float bb1 = eb1[e * DIM + c];
        const float bb2 = eb2[e * DIM + c];

        __syncthreads();   // xs ready / prev conv2 reads of ys done

        // ---- conv1 + relu: ys rows 2g,2g+1, cols 4q..4q+3 ----
        {
            const int R = 2 * g, C = 4 * q;
            float win[4][6];
            #pragma unroll
            for (int r = 0; r < 4; ++r) {
                float4 a = *(const float4*)&xs[R + r][C];
                float2 p = *(const float2*)&xs[R + r][C + 4];
                win[r][0] = a.x; win[r][1] = a.y; win[r][2] = a.z;
                win[r][3] = a.w; win[r][4] = p.x; win[r][5] = p.y;
            }
            float o0[4], o1[4];
            #pragma unroll
            for (int j = 0; j < 4; ++j) {
                float s0 = bb1, s1 = bb1;
                #pragma unroll
                for (int dr = 0; dr < 3; ++dr) {
                    s0 = fmaf(w1r[dr * 3 + 0], win[dr][j],
                         fmaf(w1r[dr * 3 + 1], win[dr][j + 1],
                         fmaf(w1r[dr * 3 + 2], win[dr][j + 2], s0)));
                    s1 = fmaf(w1r[dr * 3 + 0], win[dr + 1][j],
                         fmaf(w1r[dr * 3 + 1], win[dr + 1][j + 1],
                         fmaf(w1r[dr * 3 + 2], win[dr + 1][j + 2], s1)));
                }
                o0[j] = fmaxf(s0, 0.f);
                o1[j] = fmaxf(s1, 0.f);
            }
            if (topB && g == 0) { o0[0] = o0[1] = o0[2] = o0[3] = 0.f; }   // ys row 0 outside
            if (leftB && q == 0) { o0[0] = 0.f; o1[0] = 0.f; }             // ys col 0 outside
            *(float4*)&ys[R][C]     = make_float4(o0[0], o0[1], o0[2], o0[3]);
            *(float4*)&ys[R + 1][C] = make_float4(o1[0], o1[1], o1[2], o1[3]);
        }
        // ---- conv1 halo: ys rows 32,33 (threads 0..31) ----
        if (tid < 32) {
            int r = 32 + (tid & 1);
            int C = 4 * (tid >> 1);
            float o[4];
            #pragma unroll
            for (int j = 0; j < 4; ++j) {
                float s = bb1;
                #pragma unroll
                for (int dr = 0; dr < 3; ++dr)
                    s = fmaf(w1r[dr * 3 + 0], xs[r + dr][C + j],
                        fmaf(w1r[dr * 3 + 1], xs[r + dr][C + j + 1],
                        fmaf(w1r[dr * 3 + 2], xs[r + dr][C + j + 2], s)));
                o[j] = fmaxf(s, 0.f);
            }
            if (botB && r == 33) { o[0] = o[1] = o[2] = o[3] = 0.f; }
            if (leftB && C == 0) o[0] = 0.f;
            *(float4*)&ys[r][C] = make_float4(o[0], o[1], o[2], o[3]);
        } else if (tid < 100) {
            // ---- conv1 halo: ys cols 64,65, rows 0..33 ----
            int t2 = tid - 32;
            int cc = 64 + (t2 & 1);
            int r = t2 >> 1;                     // 0..33
            float s = bb1;
            #pragma unroll
            for (int dr = 0; dr < 3; ++dr)
                s = fmaf(w1r[dr * 3 + 0], xs[r + dr][cc],
                    fmaf(w1r[dr * 3 + 1], xs[r + dr][cc + 1],
                    fmaf(w1r[dr * 3 + 2], xs[r + dr][cc + 2], s)));
            float v = fmaxf(s, 0.f);
            if ((topB && r == 0) || (botB && r == 33) || (rightB && cc == 65)) v = 0.f;
            ys[r][cc] = v;
        }
        __syncthreads();

        // ---- conv2: out rows 2g,2g+1, cols 4q..4q+3 (ys rows 2g..2g+3, cols 4q..4q+5) ----
        {
            const int R = 2 * g, C = 4 * q;
            float win[4][6];
            #pragma unroll
            for (int r = 0; r < 4; ++r) {
                float4 a = *(const float4*)&ys[R + r][C];
                float2 p = *(const float2*)&ys[R + r][C + 4];
                win[r][0] = a.x; win[r][1] = a.y; win[r][2] = a.z;
                win[r][3] = a.w; win[r][4] = p.x; win[r][5] = p.y;
            }
            #pragma unroll
            for (int j = 0; j < 4; ++j) {
                float s0 = bb2, s1 = bb2;
                #pragma unroll
                for (int dr = 0; dr < 3; ++dr) {
                    s0 = fmaf(w2r[dr * 3 + 0], win[dr][j],
                         fmaf(w2r[dr * 3 + 1], win[dr][j + 1],
                         fmaf(w2r[dr * 3 + 2], win[dr][j + 2], s0)));
                    s1 = fmaf(w2r[dr * 3 + 0], win[dr + 1][j],
                         fmaf(w2r[dr * 3 + 1], win[dr + 1][j + 1],
                         fmaf(w2r[dr * 3 + 2], win[dr + 1][j + 2], s1)));
                }
                acc0[j] = fmaf(ce, s0, acc0[j]);
                acc1[j] = fmaf(ce, s1, acc1[j]);
            }
        }
    }

    float* op = out + ((size_t)(b * DIM + c)) * HW + (size_t)(ty0 + 2 * g) * W + tx0 + 4 * q;
    *(float4*)op       = make_float4(acc0[0], acc0[1], acc0[2], acc0[3]);
    *(float4*)(op + W) = make_float4(acc1[0], acc1[1], acc1[2], acc1[3]);
}

extern "C" void kernel_launch(void* const* d_in, const int* in_sizes, int n_in,
                              void* d_out, int out_size, void* d_ws, size_t ws_size,
                              hipStream_t stream) {
    const float* x     = (const float*)d_in[0];
    const float* w_fc0 = (const float*)d_in[1];
    const float* b_fc0 = (const float*)d_in[2];
    const float* w_fc1 = (const float*)d_in[3];
    const float* b_fc1 = (const float*)d_in[4];
    const float* ew1   = (const float*)d_in[5];
    const float* eb1   = (const float*)d_in[6];
    const float* ew2   = (const float*)d_in[7];
    const float* eb2   = (const float*)d_in[8];
    float* out = (float*)d_out;

    float* pmax = (float*)d_ws;                       // NQ*768
    float* psum = pmax + NQ * NB * DIM;               // NQ*768
    float* cof  = psum + NQ * NB * DIM;               // 48

    dim3 pg(NB * DIM, NQ);
    pool_partial<<<pg, 256, 0, stream>>>(x, pmax, psum);
    gate_kernel<<<1, 128, 0, stream>>>(pmax, psum, w_fc0, b_fc0, w_fc1, b_fc1, cof);
    dim3 grid((W / TX) * (H / TY), DIM, NB);          // (18, 96, 8)
    moe_kernel<<<grid, 256, 0, stream>>>(x, ew1, eb1, ew2, eb2, cof, out);
}